// Round 7
// baseline (397.353 us; speedup 1.0000x reference)
//
#include <hip/hip_runtime.h>
#include <math.h>

#define BB 8
#define CC 64
#define NN 32
#define CONV_TOTAL (BB*CC*NN*NN)   // 524288
#define KM_ELEMS (BB*9*CC*CC)      // 294912
#define NCANON 514                 // canonical frequencies per batch

typedef float v2f __attribute__((ext_vector_type(2)));

// readlane with compile-time lane index (uniform broadcast)
#define RL(x, l) __uint_as_float(__builtin_amdgcn_readlane(__float_as_uint(x), (l)))

// Kernel A: km[b][j][o*64+i] = 0.7*tanh(pre[b,o,i,j]) + (o==i && j==4)
// Also zeroes the 8 logdet accumulators in d_out.
__global__ __launch_bounds__(256) void build_km(const float* __restrict__ pre,
                                                float* __restrict__ km,
                                                float* __restrict__ logdet_out) {
    int idx = blockIdx.x * 256 + threadIdx.x;
    if (blockIdx.x == 0 && threadIdx.x < BB) logdet_out[threadIdx.x] = 0.f;
    if (idx >= KM_ELEMS) return;
    int b   = idx / (9 * 4096);
    int rem = idx - b * (9 * 4096);
    int j   = rem >> 12;       // tap 0..8
    int e   = rem & 4095;      // o*64+i
    int o = e >> 6, i = e & 63;
    float v = 0.7f * tanhf(pre[(b * 4096 + e) * 9 + j]);
    if (o == i && j == 4) v += 1.0f;
    km[idx] = v;
}

// Kernel B: direct circular conv. One block per (b,o); 256 threads; each
// thread owns 4 consecutive pixels in a row.
__global__ __launch_bounds__(256) void conv_kernel(const float* __restrict__ x,
                                                   const float* __restrict__ km,
                                                   const float* __restrict__ bias,
                                                   float* __restrict__ out) {
    int b = blockIdx.x >> 6, o = blockIdx.x & 63;
    __shared__ float Kms[9][64];
    __shared__ float xs[1024];
    int t = threadIdx.x;
    for (int s = t; s < 576; s += 256) {
        int j = s >> 6, i = s & 63;
        Kms[j][i] = km[(b * 9 + j) * 4096 + (o << 6) + i];
    }
    float bb = bias[(b << 6) + o];
    float acc0 = bb, acc1 = bb, acc2 = bb, acc3 = bb;
    int u = t >> 3, v0 = (t & 7) << 2;
    const float* xb = x + (size_t)(b << 6) * 1024;
    for (int i = 0; i < 64; ++i) {
        float4 xv4 = *(const float4*)(xb + i * 1024 + (t << 2));
        __syncthreads();                       // previous iter done reading xs
        *(float4*)&xs[t << 2] = xv4;
        __syncthreads();                       // xs (and Kms on iter 0) visible
        #pragma unroll
        for (int dy = 0; dy < 3; ++dy) {
            int row = (u + 1 - dy) & 31;
            const float* xr = &xs[row << 5];
            float xv[6];
            #pragma unroll
            for (int q = 0; q < 6; ++q) xv[q] = xr[(v0 - 1 + q) & 31];
            #pragma unroll
            for (int dx = 0; dx < 3; ++dx) {
                float w = Kms[dy * 3 + dx][i];
                acc0 += w * xv[2 - dx];
                acc1 += w * xv[3 - dx];
                acc2 += w * xv[4 - dx];
                acc3 += w * xv[5 - dx];
            }
        }
    }
    float4 r = make_float4(acc0, acc1, acc2, acc3);
    *(float4*)(out + ((size_t)blockIdx.x << 10) + (u << 5) + v0) = r;
}

// ---- 2-wave split-column unpivoted LU ------------------------------------
// Block = 128 threads = 2 waves per frequency. Lane = row; wave w owns
// columns c with ((c>>2)&1)==w (4-col blocks -> balanced + float4 loads).
// Local storage: v2f A[32] = 64 VGPRs -> pure arch-VGPR, 4+ waves/SIMD.
// Per step: owner wave computes per-row multipliers, publishes via
// parity-double-buffered LDS (1 barrier/step); both waves update their
// live columns with static indices (2 readlane + 4 scalar fma per col).

// local index i (0..31) <-> global col c: c = ((i>>2)<<3) + 4*wave + (i&3)
// number of owned columns with c <= K (i.e. first live local index):
constexpr int cnt_le(int K, int w) {
    int G = (K + 1) >> 3, rem = (K + 1) & 7;
    int part = rem - 4 * w;
    part = part < 0 ? 0 : (part > 4 ? 4 : part);
    return G * 4 + part;
}

template<int K>
__device__ __forceinline__ void lu_steps(v2f (&A)[32], int wave, int lane,
                                         float &lsum, v2f (*mbuf)[64]) {
    constexpr int WK = (K >> 2) & 1;                 // wave owning col K
    constexpr int IK = ((K >> 3) << 2) + (K & 3);    // its local index
    if (wave == WK) {
        float px = RL(A[IK].x, K), py = RL(A[IK].y, K);   // pivot (uniform)
        float mag = fmaf(px, px, py * py);
        lsum += 0.5f * __logf(mag);
        if constexpr (K < 63) {
            float inv = __builtin_amdgcn_rcpf(mag);
            float ax = A[IK].x, ay = A[IK].y;
            float mr = (ax * px + ay * py) * inv;    // this row's multiplier
            float mi = (ay * px - ax * py) * inv;
            bool act = lane > K;
            v2f m;
            m.x = act ? mr : 0.f;                    // rows <= K frozen
            m.y = act ? mi : 0.f;
            mbuf[K & 1][lane] = m;
        }
    }
    if constexpr (K < 63) {
        __syncthreads();                             // m visible to both waves
        v2f m = mbuf[K & 1][lane];
        if (wave == 0) {
            constexpr int I0 = cnt_le(K, 0);
            #pragma unroll
            for (int i = I0; i < 32; ++i) {
                float pcx = RL(A[i].x, K), pcy = RL(A[i].y, K);
                A[i].x = fmaf(-m.x, pcx, fmaf( m.y, pcy, A[i].x));
                A[i].y = fmaf(-m.x, pcy, fmaf(-m.y, pcx, A[i].y));
            }
        } else {
            constexpr int I0 = cnt_le(K, 1);
            #pragma unroll
            for (int i = I0; i < 32; ++i) {
                float pcx = RL(A[i].x, K), pcy = RL(A[i].y, K);
                A[i].x = fmaf(-m.x, pcx, fmaf( m.y, pcy, A[i].x));
                A[i].y = fmaf(-m.x, pcy, fmaf(-m.y, pcx, A[i].y));
            }
        }
        lu_steps<K + 1>(A, wave, lane, lsum, mbuf);
    }
}

__global__ __launch_bounds__(128, 4) void logdet_kernel(const float* __restrict__ km,
                                                        float* __restrict__ logdet_out) {
    int gid = blockIdx.x;
    int b = gid / NCANON, ci = gid - b * NCANON;
    int u, v;
    if (ci < 17)        { u = 0;                  v = ci; }
    else if (ci < 497)  { int r = ci - 17; u = 1 + (r >> 5); v = r & 31; }
    else                { u = 16;                 v = ci - 497; }
    float wgt = ((u == 0 || u == 16) && (v == 0 || v == 16)) ? 1.0f : 2.0f;

    int tid  = threadIdx.x;
    int wave = tid >> 6, lane = tid & 63;

    __shared__ v2f mbuf[2][64];                      // 1 KB, parity-buffered

    v2f A[32];
    #pragma unroll
    for (int i = 0; i < 32; ++i) A[i] = (v2f){0.f, 0.f};

    // Build this wave's 32 columns of row `lane`:
    // A[i] = sum_j km[b][j][lane*64 + c(i)] * w_j, c = 8*(i>>2)+4*wave+(i&3)
    const float* Kb = km + (size_t)b * 36864 + (lane << 6) + (wave << 2);
    #pragma unroll
    for (int j = 0; j < 9; ++j) {
        int dy = j / 3, dx = j % 3;
        float argrev = -(float)(u * (dy - 1) + v * (dx - 1)) * (1.0f / 32.0f);
        argrev = argrev - floorf(argrev);            // [0,1) revolutions
        float cs = __builtin_amdgcn_cosf(argrev);
        float sn = __builtin_amdgcn_sinf(argrev);
        v2f csn = (v2f){cs, sn};
        const float* p = Kb + (j << 12);
        #pragma unroll
        for (int q = 0; q < 8; ++q) {
            float4 k4 = *(const float4*)(p + (q << 3));   // 4 owned cols
            A[(q << 2) + 0] += csn * k4.x;
            A[(q << 2) + 1] += csn * k4.y;
            A[(q << 2) + 2] += csn * k4.z;
            A[(q << 2) + 3] += csn * k4.w;
            if ((q & 3) == 3) __builtin_amdgcn_sched_barrier(0);
        }
    }

    float lsum = 0.f;                                // this wave's pivots
    lu_steps<0>(A, wave, lane, lsum, mbuf);

    if (lane == 0) atomicAdd(&logdet_out[b], wgt * lsum);
}

extern "C" void kernel_launch(void* const* d_in, const int* in_sizes, int n_in,
                              void* d_out, int out_size, void* d_ws, size_t ws_size,
                              hipStream_t stream) {
    const float* conv_in    = (const float*)d_in[0];
    const float* pre_kernel = (const float*)d_in[1];
    const float* bias       = (const float*)d_in[2];
    float* out = (float*)d_out;
    float* km  = (float*)d_ws;                 // 294912 floats = 1.18 MB
    float* logdet_out = out + CONV_TOTAL;

    build_km<<<KM_ELEMS / 256, 256, 0, stream>>>(pre_kernel, km, logdet_out);
    conv_kernel<<<BB * CC, 256, 0, stream>>>(conv_in, km, bias, out);
    logdet_kernel<<<BB * NCANON, 128, 0, stream>>>(km, logdet_out);
}

// Round 8
// 378.268 us; speedup vs baseline: 1.0505x; 1.0505x over previous
//
#include <hip/hip_runtime.h>
#include <math.h>

#define BB 8
#define CC 64
#define NN 32
#define CONV_TOTAL (BB*CC*NN*NN)   // 524288
#define KM_ELEMS (BB*9*CC*CC)      // 294912
#define NCANON 514                 // canonical frequencies per batch

typedef float v2f __attribute__((ext_vector_type(2)));

// readlane with compile-time lane index (uniform broadcast)
#define RL(x, l) __uint_as_float(__builtin_amdgcn_readlane(__float_as_uint(x), (l)))

// Kernel A: km[b][j][o*64+i] = 0.7*tanh(pre[b,o,i,j]) + (o==i && j==4)
// Also zeroes the 8 logdet accumulators in d_out.
__global__ __launch_bounds__(256) void build_km(const float* __restrict__ pre,
                                                float* __restrict__ km,
                                                float* __restrict__ logdet_out) {
    int idx = blockIdx.x * 256 + threadIdx.x;
    if (blockIdx.x == 0 && threadIdx.x < BB) logdet_out[threadIdx.x] = 0.f;
    if (idx >= KM_ELEMS) return;
    int b   = idx / (9 * 4096);
    int rem = idx - b * (9 * 4096);
    int j   = rem >> 12;       // tap 0..8
    int e   = rem & 4095;      // o*64+i
    int o = e >> 6, i = e & 63;
    float v = 0.7f * tanhf(pre[(b * 4096 + e) * 9 + j]);
    if (o == i && j == 4) v += 1.0f;
    km[idx] = v;
}

// Kernel B: direct circular conv. One block per (b,o); 256 threads; each
// thread owns 4 consecutive pixels in a row.
__global__ __launch_bounds__(256) void conv_kernel(const float* __restrict__ x,
                                                   const float* __restrict__ km,
                                                   const float* __restrict__ bias,
                                                   float* __restrict__ out) {
    int b = blockIdx.x >> 6, o = blockIdx.x & 63;
    __shared__ float Kms[9][64];
    __shared__ float xs[1024];
    int t = threadIdx.x;
    for (int s = t; s < 576; s += 256) {
        int j = s >> 6, i = s & 63;
        Kms[j][i] = km[(b * 9 + j) * 4096 + (o << 6) + i];
    }
    float bb = bias[(b << 6) + o];
    float acc0 = bb, acc1 = bb, acc2 = bb, acc3 = bb;
    int u = t >> 3, v0 = (t & 7) << 2;
    const float* xb = x + (size_t)(b << 6) * 1024;
    for (int i = 0; i < 64; ++i) {
        float4 xv4 = *(const float4*)(xb + i * 1024 + (t << 2));
        __syncthreads();                       // previous iter done reading xs
        *(float4*)&xs[t << 2] = xv4;
        __syncthreads();                       // xs (and Kms on iter 0) visible
        #pragma unroll
        for (int dy = 0; dy < 3; ++dy) {
            int row = (u + 1 - dy) & 31;
            const float* xr = &xs[row << 5];
            float xv[6];
            #pragma unroll
            for (int q = 0; q < 6; ++q) xv[q] = xr[(v0 - 1 + q) & 31];
            #pragma unroll
            for (int dx = 0; dx < 3; ++dx) {
                float w = Kms[dy * 3 + dx][i];
                acc0 += w * xv[2 - dx];
                acc1 += w * xv[3 - dx];
                acc2 += w * xv[4 - dx];
                acc3 += w * xv[5 - dx];
            }
        }
    }
    float4 r = make_float4(acc0, acc1, acc2, acc3);
    *(float4*)(out + ((size_t)blockIdx.x << 10) + (u << 5) + v0) = r;
}

// ---- 2-wave split-column unpivoted LU ------------------------------------
// Block = 128 threads = 2 waves per frequency. Lane = row; wave w owns
// columns c with ((c>>2)&1)==w (4-col blocks -> balanced + float4 loads).
// Local storage: v2f A[32] = 64 VGPRs; true demand ~104 regs, which fits
// BOTH under the allocator's observed ~112 arch-VGPR cap (no AGPR parking)
// AND under the (128,2) budget of 256 (no scratch — R7's (128,4)=128 cap
// spilled half of A: 237MB fetch / 471MB write of scratch traffic).
// Per step: owner wave computes per-row multipliers, publishes via
// parity-double-buffered LDS (1 barrier/step); both waves update their
// live columns with static indices (2 readlane + 4 scalar fma per col).

// local index i (0..31) <-> global col c: c = ((i>>2)<<3) + 4*wave + (i&3)
// number of owned columns with c <= K (i.e. first live local index):
constexpr int cnt_le(int K, int w) {
    int G = (K + 1) >> 3, rem = (K + 1) & 7;
    int part = rem - 4 * w;
    part = part < 0 ? 0 : (part > 4 ? 4 : part);
    return G * 4 + part;
}

template<int K>
__device__ __forceinline__ void lu_steps(v2f (&A)[32], int wave, int lane,
                                         float &lsum, v2f (*mbuf)[64]) {
    constexpr int WK = (K >> 2) & 1;                 // wave owning col K
    constexpr int IK = ((K >> 3) << 2) + (K & 3);    // its local index
    if (wave == WK) {
        float px = RL(A[IK].x, K), py = RL(A[IK].y, K);   // pivot (uniform)
        float mag = fmaf(px, px, py * py);
        lsum += 0.5f * __logf(mag);
        if constexpr (K < 63) {
            float inv = __builtin_amdgcn_rcpf(mag);
            float ax = A[IK].x, ay = A[IK].y;
            float mr = (ax * px + ay * py) * inv;    // this row's multiplier
            float mi = (ay * px - ax * py) * inv;
            bool act = lane > K;
            v2f m;
            m.x = act ? mr : 0.f;                    // rows <= K frozen
            m.y = act ? mi : 0.f;
            mbuf[K & 1][lane] = m;
        }
    }
    if constexpr (K < 63) {
        __syncthreads();                             // m visible to both waves
        v2f m = mbuf[K & 1][lane];
        if (wave == 0) {
            constexpr int I0 = cnt_le(K, 0);
            #pragma unroll
            for (int i = I0; i < 32; ++i) {
                float pcx = RL(A[i].x, K), pcy = RL(A[i].y, K);
                A[i].x = fmaf(-m.x, pcx, fmaf( m.y, pcy, A[i].x));
                A[i].y = fmaf(-m.x, pcy, fmaf(-m.y, pcx, A[i].y));
            }
        } else {
            constexpr int I0 = cnt_le(K, 1);
            #pragma unroll
            for (int i = I0; i < 32; ++i) {
                float pcx = RL(A[i].x, K), pcy = RL(A[i].y, K);
                A[i].x = fmaf(-m.x, pcx, fmaf( m.y, pcy, A[i].x));
                A[i].y = fmaf(-m.x, pcy, fmaf(-m.y, pcx, A[i].y));
            }
        }
        lu_steps<K + 1>(A, wave, lane, lsum, mbuf);
    }
}

__global__ __launch_bounds__(128, 2) void logdet_kernel(const float* __restrict__ km,
                                                        float* __restrict__ logdet_out) {
    int gid = blockIdx.x;
    int b = gid / NCANON, ci = gid - b * NCANON;
    int u, v;
    if (ci < 17)        { u = 0;                  v = ci; }
    else if (ci < 497)  { int r = ci - 17; u = 1 + (r >> 5); v = r & 31; }
    else                { u = 16;                 v = ci - 497; }
    float wgt = ((u == 0 || u == 16) && (v == 0 || v == 16)) ? 1.0f : 2.0f;

    int tid  = threadIdx.x;
    int wave = tid >> 6, lane = tid & 63;

    __shared__ v2f mbuf[2][64];                      // 1 KB, parity-buffered

    v2f A[32];
    #pragma unroll
    for (int i = 0; i < 32; ++i) A[i] = (v2f){0.f, 0.f};

    // Build this wave's 32 columns of row `lane`:
    // A[i] = sum_j km[b][j][lane*64 + c(i)] * w_j, c = 8*(i>>2)+4*wave+(i&3)
    // Two float4 in flight per sched-group: keeps build-phase peak pressure
    // low (R7's 8-in-flight spike is what tripped the spill).
    const float* Kb = km + (size_t)b * 36864 + (lane << 6) + (wave << 2);
    #pragma unroll
    for (int j = 0; j < 9; ++j) {
        int dy = j / 3, dx = j % 3;
        float argrev = -(float)(u * (dy - 1) + v * (dx - 1)) * (1.0f / 32.0f);
        argrev = argrev - floorf(argrev);            // [0,1) revolutions
        float cs = __builtin_amdgcn_cosf(argrev);
        float sn = __builtin_amdgcn_sinf(argrev);
        v2f csn = (v2f){cs, sn};
        const float* p = Kb + (j << 12);
        #pragma unroll
        for (int q = 0; q < 8; q += 2) {
            float4 k4 = *(const float4*)(p + (q << 3));
            float4 k5 = *(const float4*)(p + ((q + 1) << 3));
            A[(q << 2) + 0] += csn * k4.x;
            A[(q << 2) + 1] += csn * k4.y;
            A[(q << 2) + 2] += csn * k4.z;
            A[(q << 2) + 3] += csn * k4.w;
            A[(q << 2) + 4] += csn * k5.x;
            A[(q << 2) + 5] += csn * k5.y;
            A[(q << 2) + 6] += csn * k5.z;
            A[(q << 2) + 7] += csn * k5.w;
            __builtin_amdgcn_sched_barrier(0);       // cap loads in flight
        }
    }

    float lsum = 0.f;                                // this wave's pivots
    lu_steps<0>(A, wave, lane, lsum, mbuf);

    if (lane == 0) atomicAdd(&logdet_out[b], wgt * lsum);
}

extern "C" void kernel_launch(void* const* d_in, const int* in_sizes, int n_in,
                              void* d_out, int out_size, void* d_ws, size_t ws_size,
                              hipStream_t stream) {
    const float* conv_in    = (const float*)d_in[0];
    const float* pre_kernel = (const float*)d_in[1];
    const float* bias       = (const float*)d_in[2];
    float* out = (float*)d_out;
    float* km  = (float*)d_ws;                 // 294912 floats = 1.18 MB
    float* logdet_out = out + CONV_TOTAL;

    build_km<<<KM_ELEMS / 256, 256, 0, stream>>>(pre_kernel, km, logdet_out);
    conv_kernel<<<BB * CC, 256, 0, stream>>>(conv_in, km, bias, out);
    logdet_kernel<<<BB * NCANON, 128, 0, stream>>>(km, logdet_out);
}

// Round 9
// 231.021 us; speedup vs baseline: 1.7200x; 1.6374x over previous
//
#include <hip/hip_runtime.h>
#include <math.h>

#define BB 8
#define CC 64
#define NN 32
#define CONV_TOTAL (BB*CC*NN*NN)   // 524288
#define KM_ELEMS (BB*9*CC*CC)      // 294912
#define NCANON 514                 // canonical frequencies per batch

typedef float v2f __attribute__((ext_vector_type(2)));

// readlane (uniform broadcast; lane index may be a uniform runtime value)
#define RL(x, l) __uint_as_float(__builtin_amdgcn_readlane(__float_as_uint(x), (l)))

// XOR-swizzled LDS index for v2f element (r,c): both column reads
// (fixed c, lanes=r) and row reads (fixed r, lanes=c) spread across banks
// at the 4-way b64 floor; broadcasts unaffected.
#define SW(r, c) ((((r) << 6)) | ((c) ^ (r)))

// Kernel A: km[b][j][o*64+i] = 0.7*tanh(pre[b,o,i,j]) + (o==i && j==4)
// Also zeroes the 8 logdet accumulators in d_out.
__global__ __launch_bounds__(256) void build_km(const float* __restrict__ pre,
                                                float* __restrict__ km,
                                                float* __restrict__ logdet_out) {
    int idx = blockIdx.x * 256 + threadIdx.x;
    if (blockIdx.x == 0 && threadIdx.x < BB) logdet_out[threadIdx.x] = 0.f;
    if (idx >= KM_ELEMS) return;
    int b   = idx / (9 * 4096);
    int rem = idx - b * (9 * 4096);
    int j   = rem >> 12;       // tap 0..8
    int e   = rem & 4095;      // o*64+i
    int o = e >> 6, i = e & 63;
    float v = 0.7f * tanhf(pre[(b * 4096 + e) * 9 + j]);
    if (o == i && j == 4) v += 1.0f;
    km[idx] = v;
}

// Kernel B: direct circular conv. One block per (b,o); 256 threads; each
// thread owns 4 consecutive pixels in a row.
__global__ __launch_bounds__(256) void conv_kernel(const float* __restrict__ x,
                                                   const float* __restrict__ km,
                                                   const float* __restrict__ bias,
                                                   float* __restrict__ out) {
    int b = blockIdx.x >> 6, o = blockIdx.x & 63;
    __shared__ float Kms[9][64];
    __shared__ float xs[1024];
    int t = threadIdx.x;
    for (int s = t; s < 576; s += 256) {
        int j = s >> 6, i = s & 63;
        Kms[j][i] = km[(b * 9 + j) * 4096 + (o << 6) + i];
    }
    float bb = bias[(b << 6) + o];
    float acc0 = bb, acc1 = bb, acc2 = bb, acc3 = bb;
    int u = t >> 3, v0 = (t & 7) << 2;
    const float* xb = x + (size_t)(b << 6) * 1024;
    for (int i = 0; i < 64; ++i) {
        float4 xv4 = *(const float4*)(xb + i * 1024 + (t << 2));
        __syncthreads();                       // previous iter done reading xs
        *(float4*)&xs[t << 2] = xv4;
        __syncthreads();                       // xs (and Kms on iter 0) visible
        #pragma unroll
        for (int dy = 0; dy < 3; ++dy) {
            int row = (u + 1 - dy) & 31;
            const float* xr = &xs[row << 5];
            float xv[6];
            #pragma unroll
            for (int q = 0; q < 6; ++q) xv[q] = xr[(v0 - 1 + q) & 31];
            #pragma unroll
            for (int dx = 0; dx < 3; ++dx) {
                float w = Kms[dy * 3 + dx][i];
                acc0 += w * xv[2 - dx];
                acc1 += w * xv[3 - dx];
                acc2 += w * xv[4 - dx];
                acc3 += w * xv[5 - dx];
            }
        }
    }
    float4 r = make_float4(acc0, acc1, acc2, acc3);
    *(float4*)(out + ((size_t)blockIdx.x << 10) + (u << 5) + v0) = r;
}

// Kernel C: blocked unpivoted LU in LDS, panel width 8.
// 256 threads / block, one canonical frequency per block.
// Per panel p: wave 0 factors the 8-col panel in registers (no barriers,
// intra-wave readlane broadcasts) and solves the 8xT U-block; barrier;
// all 4 waves apply the rank-8 Schur update (L in regs, U broadcast,
// v_pk_fma complex MACs); barrier. 16 barriers total.
__global__ __launch_bounds__(256, 3) void logdet_kernel(const float* __restrict__ km,
                                                        float* __restrict__ logdet_out) {
    int gid = blockIdx.x;
    int b = gid / NCANON, ci = gid - b * NCANON;
    int u, v;
    if (ci < 17)        { u = 0;                  v = ci; }
    else if (ci < 497)  { int r = ci - 17; u = 1 + (r >> 5); v = r & 31; }
    else                { u = 16;                 v = ci - 497; }
    float wgt = ((u == 0 || u == 16) && (v == 0 || v == 16)) ? 1.0f : 2.0f;

    int t = threadIdx.x;
    int wave = t >> 6, lane = t & 63;

    __shared__ v2f As[4096];                         // 32 KB, swizzled

    // twiddles w[j] = exp(-2*pi*i*(u*(dy-1)+v*(dx-1))/32) via HW sin/cos
    float wr[9], wi[9];
    #pragma unroll
    for (int j = 0; j < 9; ++j) {
        int dy = j / 3, dx = j % 3;
        float argrev = -(float)(u * (dy - 1) + v * (dx - 1)) * (1.0f / 32.0f);
        argrev = argrev - floorf(argrev);            // [0,1) revolutions
        wr[j] = __builtin_amdgcn_cosf(argrev);
        wi[j] = __builtin_amdgcn_sinf(argrev);
    }

    // Build A[r][c] = sum_j km[b][j][r*64+c] * w_j  (c fast -> coalesced)
    const float* Kb = km + (size_t)b * 36864;
    #pragma unroll
    for (int rep = 0; rep < 16; ++rep) {
        int e = t + (rep << 8);
        int r = e >> 6, c = e & 63;
        float re = 0.f, im = 0.f;
        #pragma unroll
        for (int j = 0; j < 9; ++j) {
            float kv = Kb[(j << 12) + e];
            re = fmaf(kv, wr[j], re);
            im = fmaf(kv, wi[j], im);
        }
        As[SW(r, c)] = (v2f){re, im};
    }
    __syncthreads();

    float lsum = 0.f;                                // meaningful in wave 0
    for (int p = 0; p < 8; ++p) {
        int K0 = p << 3, K7 = K0 | 7;
        if (wave == 0) {
            // ---- panel factorization (rows = lanes, cols K0..K7 in regs)
            int r = lane;
            v2f pc[8];
            #pragma unroll
            for (int j = 0; j < 8; ++j) pc[j] = As[SW(r, K0 + j)];
            #pragma unroll
            for (int k = 0; k < 8; ++k) {
                int K = K0 + k;
                float px = RL(pc[k].x, K), py = RL(pc[k].y, K);
                float mag = fmaf(px, px, py * py);
                lsum += 0.5f * __logf(mag);
                float inv = __builtin_amdgcn_rcpf(mag);
                float mr = (pc[k].x * px + pc[k].y * py) * inv;
                float mi = (pc[k].y * px - pc[k].x * py) * inv;
                bool act = r > K;
                mr = act ? mr : 0.f;                 // rows <= K frozen
                mi = act ? mi : 0.f;
                pc[k].x = act ? mr : pc[k].x;        // store multiplier
                pc[k].y = act ? mi : pc[k].y;
                #pragma unroll
                for (int j = k + 1; j < 8; ++j) {
                    float ux = RL(pc[j].x, K), uy = RL(pc[j].y, K);
                    pc[j].x = fmaf(-mr, ux, fmaf( mi, uy, pc[j].x));
                    pc[j].y = fmaf(-mr, uy, fmaf(-mi, ux, pc[j].y));
                }
            }
            #pragma unroll
            for (int j = 0; j < 8; ++j) As[SW(r, K0 + j)] = pc[j];

            // ---- U-block triangular solve (cols = lanes), trailing cols
            if (p < 7) {
                int c = lane;
                v2f uu[8];
                #pragma unroll
                for (int j = 0; j < 8; ++j) uu[j] = As[SW(K0 + j, c)];
                #pragma unroll
                for (int j = 1; j < 8; ++j) {
                    #pragma unroll
                    for (int j2 = 0; j2 < 8; ++j2) {
                        if (j2 >= j) continue;
                        v2f L = As[SW(K0 + j, K0 + j2)];   // broadcast
                        uu[j].x = fmaf(-L.x, uu[j2].x, fmaf( L.y, uu[j2].y, uu[j].x));
                        uu[j].y = fmaf(-L.x, uu[j2].y, fmaf(-L.y, uu[j2].x, uu[j].y));
                    }
                }
                if (c > K7) {
                    #pragma unroll
                    for (int j = 0; j < 8; ++j) As[SW(K0 + j, c)] = uu[j];
                }
            }
        }
        __syncthreads();
        if (p < 7) {
            // ---- rank-8 Schur update: all 4 waves, rows = lanes,
            // wave w covers cols c = (i<<2)|w (uniform skip if c <= K7)
            int r = lane;
            bool actr = r > K7;
            v2f l1[8], l2[8];
            #pragma unroll
            for (int j = 0; j < 8; ++j) {
                v2f L = As[SW(r, K0 + j)];
                float lx = actr ? L.x : 0.f;         // frozen rows: L = 0
                float ly = actr ? L.y : 0.f;
                l1[j] = (v2f){-lx, -lx};
                l2[j] = (v2f){ ly, -ly};
            }
            for (int i = 0; i < 16; ++i) {
                int c = (i << 2) | wave;
                if (c > K7) {
                    v2f a = As[SW(r, c)];
                    #pragma unroll
                    for (int j = 0; j < 8; ++j) {
                        v2f U = As[SW(K0 + j, c)];   // broadcast
                        v2f u2 = (v2f){U.y, U.x};
                        a = l1[j] * U  + a;          // v_pk_fma_f32
                        a = l2[j] * u2 + a;
                    }
                    As[SW(r, c)] = a;
                }
            }
        }
        __syncthreads();
    }
    if (t == 0) atomicAdd(&logdet_out[b], wgt * lsum);
}

extern "C" void kernel_launch(void* const* d_in, const int* in_sizes, int n_in,
                              void* d_out, int out_size, void* d_ws, size_t ws_size,
                              hipStream_t stream) {
    const float* conv_in    = (const float*)d_in[0];
    const float* pre_kernel = (const float*)d_in[1];
    const float* bias       = (const float*)d_in[2];
    float* out = (float*)d_out;
    float* km  = (float*)d_ws;                 // 294912 floats = 1.18 MB
    float* logdet_out = out + CONV_TOTAL;

    build_km<<<KM_ELEMS / 256, 256, 0, stream>>>(pre_kernel, km, logdet_out);
    conv_kernel<<<BB * CC, 256, 0, stream>>>(conv_in, km, bias, out);
    logdet_kernel<<<BB * NCANON, 256, 0, stream>>>(km, logdet_out);
}

// Round 10
// 230.186 us; speedup vs baseline: 1.7262x; 1.0036x over previous
//
#include <hip/hip_runtime.h>
#include <math.h>

#define BB 8
#define CC 64
#define NN 32
#define CONV_TOTAL (BB*CC*NN*NN)   // 524288
#define KM_ELEMS (BB*9*CC*CC)      // 294912
#define NCANON 514                 // canonical frequencies per batch

typedef float v2f __attribute__((ext_vector_type(2)));

// readlane (uniform broadcast; lane index may be a uniform runtime value)
#define RL(x, l) __uint_as_float(__builtin_amdgcn_readlane(__float_as_uint(x), (l)))

// Pair-granular swizzled LDS index: pair (r, cp) -> float4 slot.
// Column-direction access (fixed cp, r=lanes) spreads across banks.
#define PIDX(r, cp) (((r) << 5) | ((cp) ^ ((r) & 31)))

// Kernel A: km[b][j][o*64+i] = 0.7*tanh(pre[b,o,i,j]) + (o==i && j==4)
// Also zeroes the 8 logdet accumulators in d_out.
__global__ __launch_bounds__(256) void build_km(const float* __restrict__ pre,
                                                float* __restrict__ km,
                                                float* __restrict__ logdet_out) {
    int idx = blockIdx.x * 256 + threadIdx.x;
    if (blockIdx.x == 0 && threadIdx.x < BB) logdet_out[threadIdx.x] = 0.f;
    if (idx >= KM_ELEMS) return;
    int b   = idx / (9 * 4096);
    int rem = idx - b * (9 * 4096);
    int j   = rem >> 12;       // tap 0..8
    int e   = rem & 4095;      // o*64+i
    int o = e >> 6, i = e & 63;
    float v = 0.7f * tanhf(pre[(b * 4096 + e) * 9 + j]);
    if (o == i && j == 4) v += 1.0f;
    km[idx] = v;
}

// Kernel B: direct circular conv. One block per (b,o); 256 threads; each
// thread owns 4 consecutive pixels in a row.
__global__ __launch_bounds__(256) void conv_kernel(const float* __restrict__ x,
                                                   const float* __restrict__ km,
                                                   const float* __restrict__ bias,
                                                   float* __restrict__ out) {
    int b = blockIdx.x >> 6, o = blockIdx.x & 63;
    __shared__ float Kms[9][64];
    __shared__ float xs[1024];
    int t = threadIdx.x;
    for (int s = t; s < 576; s += 256) {
        int j = s >> 6, i = s & 63;
        Kms[j][i] = km[(b * 9 + j) * 4096 + (o << 6) + i];
    }
    float bb = bias[(b << 6) + o];
    float acc0 = bb, acc1 = bb, acc2 = bb, acc3 = bb;
    int u = t >> 3, v0 = (t & 7) << 2;
    const float* xb = x + (size_t)(b << 6) * 1024;
    for (int i = 0; i < 64; ++i) {
        float4 xv4 = *(const float4*)(xb + i * 1024 + (t << 2));
        __syncthreads();                       // previous iter done reading xs
        *(float4*)&xs[t << 2] = xv4;
        __syncthreads();                       // xs (and Kms on iter 0) visible
        #pragma unroll
        for (int dy = 0; dy < 3; ++dy) {
            int row = (u + 1 - dy) & 31;
            const float* xr = &xs[row << 5];
            float xv[6];
            #pragma unroll
            for (int q = 0; q < 6; ++q) xv[q] = xr[(v0 - 1 + q) & 31];
            #pragma unroll
            for (int dx = 0; dx < 3; ++dx) {
                float w = Kms[dy * 3 + dx][i];
                acc0 += w * xv[2 - dx];
                acc1 += w * xv[3 - dx];
                acc2 += w * xv[4 - dx];
                acc3 += w * xv[5 - dx];
            }
        }
    }
    float4 r = make_float4(acc0, acc1, acc2, acc3);
    *(float4*)(out + ((size_t)blockIdx.x << 10) + (u << 5) + v0) = r;
}

// Kernel C: blocked unpivoted LU in LDS, panel width 8, W-form Schur.
// Matrix stored as 64x32 column-PAIRS (float4 = 2 complex), pair-swizzled.
// Per panel p: wave0 factors the 8-col panel in registers + inverts the
// 8x8 unit-lower block (Linv, lanes 0-7); all waves form W = L_trail*Linv
// (wave w -> W cols 2w,2w+1, written back into the dead panel columns);
// all waves apply Schur A -= W * A_top using RAW top-block pairs as
// uniform b128 broadcasts -- the U-block is never materialized.
__global__ __launch_bounds__(256, 3) void logdet_kernel(const float* __restrict__ km,
                                                        float* __restrict__ logdet_out) {
    int gid = blockIdx.x;
    int b = gid / NCANON, ci = gid - b * NCANON;
    int u, v;
    if (ci < 17)        { u = 0;                  v = ci; }
    else if (ci < 497)  { int r = ci - 17; u = 1 + (r >> 5); v = r & 31; }
    else                { u = 16;                 v = ci - 497; }
    float wgt = ((u == 0 || u == 16) && (v == 0 || v == 16)) ? 1.0f : 2.0f;

    int t = threadIdx.x;
    int wave = t >> 6, lane = t & 63;

    __shared__ float4 As[2048];                      // 32 KB pair-swizzled
    __shared__ v2f LinvS[8][8];                      // Linv[t][j] (0 for t<j)

    // twiddles w[j] = exp(-2*pi*i*(u*(dy-1)+v*(dx-1))/32) via HW sin/cos
    float wr[9], wi[9];
    #pragma unroll
    for (int j = 0; j < 9; ++j) {
        int dy = j / 3, dx = j % 3;
        float argrev = -(float)(u * (dy - 1) + v * (dx - 1)) * (1.0f / 32.0f);
        argrev = argrev - floorf(argrev);            // [0,1) revolutions
        wr[j] = __builtin_amdgcn_cosf(argrev);
        wi[j] = __builtin_amdgcn_sinf(argrev);
    }

    // Build: 8 pairs/thread. A[r][c] = sum_j km[b][j][r*64+c] * w_j
    const float* Kb = km + (size_t)b * 36864;
    #pragma unroll
    for (int rep = 0; rep < 8; ++rep) {
        int e2 = t + (rep << 8);                     // pair index
        int r = e2 >> 5, cp = e2 & 31;
        int e = e2 << 1;                             // element r*64 + 2*cp
        float re0 = 0.f, im0 = 0.f, re1 = 0.f, im1 = 0.f;
        #pragma unroll
        for (int j = 0; j < 9; ++j) {
            float2 kv = *(const float2*)(Kb + (j << 12) + e);
            re0 = fmaf(kv.x, wr[j], re0); im0 = fmaf(kv.x, wi[j], im0);
            re1 = fmaf(kv.y, wr[j], re1); im1 = fmaf(kv.y, wi[j], im1);
        }
        As[PIDX(r, cp)] = make_float4(re0, im0, re1, im1);
    }
    __syncthreads();

    float lsum = 0.f;                                // meaningful in wave 0
    for (int p = 0; p < 8; ++p) {
        int K0 = p << 3, K7 = K0 | 7;
        int pb = p << 2;                             // panel pair base
        if (wave == 0) {
            // ---- panel factorization, rows = lanes, 8 cols in regs
            int r = lane;
            v2f pc[8];
            #pragma unroll
            for (int q = 0; q < 4; ++q) {
                float4 f = As[PIDX(r, pb + q)];
                pc[2*q]   = (v2f){f.x, f.y};
                pc[2*q+1] = (v2f){f.z, f.w};
            }
            #pragma unroll
            for (int k = 0; k < 8; ++k) {
                int K = K0 + k;
                float px = RL(pc[k].x, K), py = RL(pc[k].y, K);
                float mag = fmaf(px, px, py * py);
                lsum += 0.5f * __logf(mag);
                float inv = __builtin_amdgcn_rcpf(mag);
                float mr = (pc[k].x * px + pc[k].y * py) * inv;
                float mi = (pc[k].y * px - pc[k].x * py) * inv;
                bool act = r > K;
                mr = act ? mr : 0.f; mi = act ? mi : 0.f;
                pc[k].x = act ? mr : pc[k].x;        // store multiplier (L)
                pc[k].y = act ? mi : pc[k].y;
                #pragma unroll
                for (int j = k + 1; j < 8; ++j) {
                    float ux = RL(pc[j].x, K), uy = RL(pc[j].y, K);
                    pc[j].x = fmaf(-mr, ux, fmaf( mi, uy, pc[j].x));
                    pc[j].y = fmaf(-mr, uy, fmaf(-mi, ux, pc[j].y));
                }
            }
            #pragma unroll
            for (int q = 0; q < 4; ++q)
                As[PIDX(r, pb + q)] =
                    make_float4(pc[2*q].x, pc[2*q].y, pc[2*q+1].x, pc[2*q+1].y);

            // ---- Linv of the 8x8 unit-lower block: lane q -> column q
            if (p < 7) {
                v2f x[8];
                #pragma unroll
                for (int j = 0; j < 8; ++j)
                    x[j] = (v2f){(lane == j) ? 1.f : 0.f, 0.f};
                #pragma unroll
                for (int j = 1; j < 8; ++j) {
                    #pragma unroll
                    for (int tq = 0; tq < j; ++tq) {
                        float ljx = RL(pc[tq].x, K0 + j);
                        float ljy = RL(pc[tq].y, K0 + j);
                        x[j].x = fmaf(-ljx, x[tq].x, fmaf( ljy, x[tq].y, x[j].x));
                        x[j].y = fmaf(-ljx, x[tq].y, fmaf(-ljy, x[tq].x, x[j].y));
                    }
                }
                if (lane < 8) {
                    #pragma unroll
                    for (int j = 0; j < 8; ++j) LinvS[j][lane] = x[j];
                }
            }
        }
        __syncthreads();                             // b1: panel + Linv visible
        if (p < 7) {
            int r = lane;
            // ---- W = L_trail * Linv : this wave computes cols 2w, 2w+1
            v2f l8[8];
            #pragma unroll
            for (int q = 0; q < 4; ++q) {
                float4 f = As[PIDX(r, pb + q)];
                l8[2*q]   = (v2f){f.x, f.y};
                l8[2*q+1] = (v2f){f.z, f.w};
            }
            v2f W0 = (v2f){0.f, 0.f}, W1 = (v2f){0.f, 0.f};
            #pragma unroll
            for (int tq = 0; tq < 8; ++tq) {
                v2f Lt = l8[tq];
                v2f i0 = LinvS[tq][2*wave];          // uniform broadcast
                v2f i1 = LinvS[tq][2*wave + 1];
                W0.x = fmaf(Lt.x, i0.x, fmaf(-Lt.y, i0.y, W0.x));
                W0.y = fmaf(Lt.x, i0.y, fmaf( Lt.y, i0.x, W0.y));
                W1.x = fmaf(Lt.x, i1.x, fmaf(-Lt.y, i1.y, W1.x));
                W1.y = fmaf(Lt.x, i1.y, fmaf( Lt.y, i1.x, W1.y));
            }
            __syncthreads();                         // b2: all L reads done
            if (r > K7)
                As[PIDX(r, pb + wave)] = make_float4(W0.x, W0.y, W1.x, W1.y);
            __syncthreads();                         // b3: W visible

            // ---- Schur: A[r][c] -= W(r,:) . A_top(:,c), pairs cp += 4
            v2f wn1[8], wn2[8];
            bool actr = r > K7;
            #pragma unroll
            for (int q = 0; q < 4; ++q) {
                float4 f = As[PIDX(r, pb + q)];
                float w0x = actr ? f.x : 0.f, w0y = actr ? f.y : 0.f;
                float w1x = actr ? f.z : 0.f, w1y = actr ? f.w : 0.f;
                wn1[2*q]   = (v2f){-w0x, -w0x};  wn2[2*q]   = (v2f){ w0y, -w0y};
                wn1[2*q+1] = (v2f){-w1x, -w1x};  wn2[2*q+1] = (v2f){ w1y, -w1y};
            }
            for (int cp = pb + 4 + wave; cp < 32; cp += 4) {
                float4 a = As[PIDX(r, cp)];
                v2f a0 = (v2f){a.x, a.y}, a1 = (v2f){a.z, a.w};
                #pragma unroll
                for (int j = 0; j < 8; ++j) {
                    float4 Tp = As[PIDX(K0 + j, cp)];     // uniform A_top pair
                    v2f T0 = (v2f){Tp.x, Tp.y}, T1 = (v2f){Tp.z, Tp.w};
                    a0 = wn1[j] * T0 + a0;               // v_pk_fma_f32
                    a0 = wn2[j] * (v2f){T0.y, T0.x} + a0;
                    a1 = wn1[j] * T1 + a1;
                    a1 = wn2[j] * (v2f){T1.y, T1.x} + a1;
                }
                if (actr) As[PIDX(r, cp)] = make_float4(a0.x, a0.y, a1.x, a1.y);
            }
        }
        __syncthreads();                             // b_A: panel complete
    }
    if (t == 0) atomicAdd(&logdet_out[b], wgt * lsum);
}

extern "C" void kernel_launch(void* const* d_in, const int* in_sizes, int n_in,
                              void* d_out, int out_size, void* d_ws, size_t ws_size,
                              hipStream_t stream) {
    const float* conv_in    = (const float*)d_in[0];
    const float* pre_kernel = (const float*)d_in[1];
    const float* bias       = (const float*)d_in[2];
    float* out = (float*)d_out;
    float* km  = (float*)d_ws;                 // 294912 floats = 1.18 MB
    float* logdet_out = out + CONV_TOTAL;

    build_km<<<KM_ELEMS / 256, 256, 0, stream>>>(pre_kernel, km, logdet_out);
    conv_kernel<<<BB * CC, 256, 0, stream>>>(conv_in, km, bias, out);
    logdet_kernel<<<BB * NCANON, 256, 0, stream>>>(km, logdet_out);
}